// Round 6
// baseline (223.506 us; speedup 1.0000x reference)
//
#include <hip/hip_runtime.h>
#include <hip/hip_bf16.h>
#include <stdint.h>

// Workload (fixed):
//   x:            [B=32, L=4096, D=768] f32 (shape only)
//   topic_vectors:[T=2048, D=768] f32
//   out:          [B, L, T] f32 -- 1 GiB, batch-broadcast of a [L,T] 0/1 map.
// softmax monotone -> top_k(softmax(tv)) idx == top_k(tv) idx; idx < D=768 so
// `% L` is identity -> rows l >= 768 are all zero (80% of output).
//
// Roofline note (R1-R5): all fill variants sustain ~5.3-5.4 TB/s on d_out
// (incl. in-graph hipMemsetAsync); the 6.5 TB/s rocclr figure holds only for
// the 4-GiB workspace poison fills. The op is an irreducible 1.074-GB write.

#define B_DIM    32
#define L_DIM    4096
#define D_DIM    768
#define T_TOPICS 2048
#define K_TOP    16

#define WORDS_PER_ROW (T_TOPICS / 32)             // 64 u32 per l-row
#define BITMAP_WORDS  (D_DIM * WORDS_PER_ROW)     // 49152 words = 192 KiB
#define PLANE4    (L_DIM * (T_TOPICS / 4))        // float4 per plane = 2,097,152
#define CHUNK4    2048                            // float4 per chunk (32 KiB)
#define BM_CHUNKS (D_DIM * (T_TOPICS / 4) / CHUNK4)  // chunks with l<768 = 192
#define ALL_CHUNKS (PLANE4 / CHUNK4)              // chunks per plane = 1024

typedef float f32x4 __attribute__((ext_vector_type(4)));

__global__ void zero_bitmap_kernel(uint32_t* __restrict__ bm) {
    int i = blockIdx.x * blockDim.x + threadIdx.x;
    if (i < BITMAP_WORDS) bm[i] = 0u;
}

// One wave per topic; 16x wave-argmax (tie -> smaller index, = jax top_k),
// set bit (l=idx, t=topic) in the [D_DIM][T_TOPICS] bitmap.
__global__ void topk_kernel(const float* __restrict__ tv, uint32_t* __restrict__ bm) {
    const int t    = blockIdx.x;
    const int lane = threadIdx.x;
    const float* __restrict__ row = tv + (size_t)t * D_DIM;

    float v[D_DIM / 64];                 // 12 values, idx = lane + j*64
    #pragma unroll
    for (int j = 0; j < D_DIM / 64; ++j) v[j] = row[lane + j * 64];

    for (int k = 0; k < K_TOP; ++k) {
        float bv = v[0];
        int   bj = 0;
        #pragma unroll
        for (int j = 1; j < D_DIM / 64; ++j) {
            if (v[j] > bv) { bv = v[j]; bj = j; }
        }
        float cv = bv;
        int   ci = lane + bj * 64;
        #pragma unroll
        for (int off = 32; off > 0; off >>= 1) {
            float ov = __shfl_xor(cv, off);
            int   oi = __shfl_xor(ci, off);
            if (ov > cv || (ov == cv && oi < ci)) { cv = ov; ci = oi; }
        }
        if ((ci & 63) == lane) v[ci >> 6] = -INFINITY;
        if (lane == 0) {
            atomicOr(&bm[ci * WORDS_PER_ROW + (t >> 5)], 1u << (t & 31));
        }
    }
}

// Fused fill: grid (1024 chunks, 32 batches), 256 threads, 8 float4/thread
// (128 B/thread, 32 KiB/block). Chunk c < 192 -> bitmap region (l < 768):
// one hot-L2 dword load per 64 B. c >= 192 -> pure zero stream. Branch is
// block-uniform. nt stores: 1 GiB pure stream, never re-read.
__global__ __launch_bounds__(256) void fill_kernel(const uint32_t* __restrict__ bm,
                                                   f32x4* __restrict__ out) {
    const unsigned c = blockIdx.x;                       // 0..1023 within plane
    f32x4* p = out + (size_t)blockIdx.y * PLANE4 + c * (unsigned)CHUNK4 + threadIdx.x;

    if (c >= (unsigned)BM_CHUNKS) {
        const f32x4 z = {0.f, 0.f, 0.f, 0.f};
        #pragma unroll
        for (int s = 0; s < 8; ++s)
            __builtin_nontemporal_store(z, p + s * 256);
    } else {
        const unsigned base = c * (unsigned)CHUNK4 + threadIdx.x;
        #pragma unroll
        for (int s = 0; s < 8; ++s) {
            const unsigned idx = base + s * 256u;        // < 393,216 -> l < 768
            const int l  = (int)(idx >> 9);
            const int t4 = (int)(idx & 511u);
            const uint32_t w  = bm[l * WORDS_PER_ROW + (t4 >> 3)];
            const int sh = (t4 & 7) * 4;
            f32x4 val;
            val.x = ((w >> (sh + 0)) & 1u) ? 1.0f : 0.0f;
            val.y = ((w >> (sh + 1)) & 1u) ? 1.0f : 0.0f;
            val.z = ((w >> (sh + 2)) & 1u) ? 1.0f : 0.0f;
            val.w = ((w >> (sh + 3)) & 1u) ? 1.0f : 0.0f;
            __builtin_nontemporal_store(val, p + s * 256);
        }
    }
}

extern "C" void kernel_launch(void* const* d_in, const int* in_sizes, int n_in,
                              void* d_out, int out_size, void* d_ws, size_t ws_size,
                              hipStream_t stream) {
    const float* tv  = (const float*)d_in[1];   // topic_vectors [T, D]
    f32x4*       out = (f32x4*)d_out;           // [B, L, T] f32
    uint32_t*    bm  = (uint32_t*)d_ws;         // 192 KiB bitmap

    hipLaunchKernelGGL(zero_bitmap_kernel,
                       dim3((BITMAP_WORDS + 255) / 256), dim3(256), 0, stream, bm);
    hipLaunchKernelGGL(topk_kernel,
                       dim3(T_TOPICS), dim3(64), 0, stream, tv, bm);
    hipLaunchKernelGGL(fill_kernel,
                       dim3(ALL_CHUNKS, B_DIM), dim3(256), 0, stream, bm, out);
}

// Round 7
// 215.584 us; speedup vs baseline: 1.0367x; 1.0367x over previous
//
#include <hip/hip_runtime.h>
#include <hip/hip_bf16.h>
#include <stdint.h>

// Workload (fixed):
//   x:            [B=32, L=4096, D=768] f32 (shape only)
//   topic_vectors:[T=2048, D=768] f32
//   out:          [B, L, T] f32 -- 1 GiB, batch-broadcast of a [L,T] 0/1 map.
// softmax monotone -> top_k(softmax(tv)) idx == top_k(tv) idx; idx < D=768 so
// `% L` is identity -> rows l >= 768 are all zero (80% of output).
//
// Roofline (R1-R6): the op is an irreducible 1.074-GB output write. All six
// structural variants (grid-stride / split / fused / nt / memset+sparse /
// 8xf4) land at 215.6-244.9 us; effective store BW on d_out saturates at
// ~5.3-5.4 TB/s under graph replay (in-graph memset ~5.6 TB/s). This file is
// the best-measured variant (R4, 215.6 us): fused fill, 4 float4/thread, nt.

#define B_DIM    32
#define L_DIM    4096
#define D_DIM    768
#define T_TOPICS 2048
#define K_TOP    16

#define WORDS_PER_ROW (T_TOPICS / 32)            // 64 u32 per l-row
#define BITMAP_WORDS  (D_DIM * WORDS_PER_ROW)    // 49152 words = 192 KiB
#define PLANE4   (L_DIM * (T_TOPICS / 4))        // float4 per batch plane = 2,097,152
#define BM_CHUNKS (D_DIM * (T_TOPICS / 4) / 1024) // chunks (1024 float4) with l<768 = 384
#define ALL_CHUNKS (PLANE4 / 1024)               // chunks per plane = 2048

typedef float f32x4 __attribute__((ext_vector_type(4)));

__global__ void zero_bitmap_kernel(uint32_t* __restrict__ bm) {
    int i = blockIdx.x * blockDim.x + threadIdx.x;
    if (i < BITMAP_WORDS) bm[i] = 0u;
}

// One wave per topic; 16x wave-argmax (tie -> smaller index, = jax top_k),
// set bit (l=idx, t=topic) in the [D_DIM][T_TOPICS] bitmap.
__global__ void topk_kernel(const float* __restrict__ tv, uint32_t* __restrict__ bm) {
    const int t    = blockIdx.x;
    const int lane = threadIdx.x;
    const float* __restrict__ row = tv + (size_t)t * D_DIM;

    float v[D_DIM / 64];                 // 12 values, idx = lane + j*64
    #pragma unroll
    for (int j = 0; j < D_DIM / 64; ++j) v[j] = row[lane + j * 64];

    for (int k = 0; k < K_TOP; ++k) {
        float bv = v[0];
        int   bj = 0;
        #pragma unroll
        for (int j = 1; j < D_DIM / 64; ++j) {
            if (v[j] > bv) { bv = v[j]; bj = j; }
        }
        float cv = bv;
        int   ci = lane + bj * 64;
        #pragma unroll
        for (int off = 32; off > 0; off >>= 1) {
            float ov = __shfl_xor(cv, off);
            int   oi = __shfl_xor(ci, off);
            if (ov > cv || (ov == cv && oi < ci)) { cv = ov; ci = oi; }
        }
        if ((ci & 63) == lane) v[ci >> 6] = -INFINITY;
        if (lane == 0) {
            atomicOr(&bm[ci * WORDS_PER_ROW + (t >> 5)], 1u << (t & 31));
        }
    }
}

// Fused fill: grid (2048 chunks, 32 batches), 256 threads, 4 float4/thread.
// Chunk c < 384 -> bitmap region (l < 768): 1 hot-L2 dword load per 64 B.
// Chunk c >= 384 -> pure zero stream. Branch is block-uniform (no divergence).
// nt stores: 1 GiB pure stream, never re-read.
__global__ __launch_bounds__(256) void fill_kernel(const uint32_t* __restrict__ bm,
                                                   f32x4* __restrict__ out) {
    const unsigned c = blockIdx.x;                       // 0..2047 within plane
    f32x4* p = out + (size_t)blockIdx.y * PLANE4 + c * 1024u + threadIdx.x;

    if (c >= (unsigned)BM_CHUNKS) {
        const f32x4 z = {0.f, 0.f, 0.f, 0.f};
        __builtin_nontemporal_store(z, p);
        __builtin_nontemporal_store(z, p + 256);
        __builtin_nontemporal_store(z, p + 512);
        __builtin_nontemporal_store(z, p + 768);
    } else {
        const unsigned base = c * 1024u + threadIdx.x;
        #pragma unroll
        for (int s = 0; s < 4; ++s) {
            const unsigned idx = base + s * 256u;        // < 393,216 -> l < 768
            const int l  = (int)(idx >> 9);
            const int t4 = (int)(idx & 511u);
            const uint32_t w  = bm[l * WORDS_PER_ROW + (t4 >> 3)];
            const int sh = (t4 & 7) * 4;
            f32x4 val;
            val.x = ((w >> (sh + 0)) & 1u) ? 1.0f : 0.0f;
            val.y = ((w >> (sh + 1)) & 1u) ? 1.0f : 0.0f;
            val.z = ((w >> (sh + 2)) & 1u) ? 1.0f : 0.0f;
            val.w = ((w >> (sh + 3)) & 1u) ? 1.0f : 0.0f;
            __builtin_nontemporal_store(val, p + s * 256);
        }
    }
}

extern "C" void kernel_launch(void* const* d_in, const int* in_sizes, int n_in,
                              void* d_out, int out_size, void* d_ws, size_t ws_size,
                              hipStream_t stream) {
    const float* tv  = (const float*)d_in[1];   // topic_vectors [T, D]
    f32x4*       out = (f32x4*)d_out;           // [B, L, T] f32
    uint32_t*    bm  = (uint32_t*)d_ws;         // 192 KiB bitmap

    hipLaunchKernelGGL(zero_bitmap_kernel,
                       dim3((BITMAP_WORDS + 255) / 256), dim3(256), 0, stream, bm);
    hipLaunchKernelGGL(topk_kernel,
                       dim3(T_TOPICS), dim3(64), 0, stream, tv, bm);
    hipLaunchKernelGGL(fill_kernel,
                       dim3(ALL_CHUNKS, B_DIM), dim3(256), 0, stream, bm, out);
}